// Round 5
// baseline (2626.301 us; speedup 1.0000x reference)
//
#include <hip/hip_runtime.h>

// ODELayer RK4 scan. R5 structure:
//   Phase 1 (scan_kernel, 64 WG x 256 thr = 4 waves): 256-step RK4 chain.
//     4 waves/WG halves redundant LDS b128 reads vs R4's 8 waves (DS-pipe
//     instruction throughput is the measured bottleneck). Each wave holds
//     312 VGPRs of dx-net weight B-fragments (1 wave/SIMD). RK4 state in
//     C-layout registers. 12 barriers/step. Writes x_new (bf16) to scratch.
//   Phase 2 (outnet_kernel, 512 WG x 512 thr): unchanged from R4.
// All global data f32; MFMA math bf16, f32 accumulate.

#define TSTEPS 256
#define BATCH  1024
#define NUQ    32
#define NXQ    128
#define NFQ    256
#define NINQ   160
#define NY     ((size_t)TSTEPS * BATCH * NXQ)

typedef __attribute__((ext_vector_type(8))) short bf16x8;
typedef __attribute__((ext_vector_type(4))) short s16x4;
typedef __attribute__((ext_vector_type(4))) float f32x4;
typedef unsigned short u16;

__device__ __forceinline__ u16 f2b(float f) {
  unsigned u = __float_as_uint(f);
  u = (u + 0x7FFFu + ((u >> 16) & 1u)) >> 16;
  return (u16)u;
}
__device__ __forceinline__ f32x4 mfma16(bf16x8 a, bf16x8 b, f32x4 c) {
  return __builtin_amdgcn_mfma_f32_16x16x32_bf16(a, b, c, 0, 0, 0);
}
__device__ __forceinline__ bf16x8 ldw8f(const float* p) {
  f32x4 a = *reinterpret_cast<const f32x4*>(p);
  f32x4 b = *reinterpret_cast<const f32x4*>(p + 4);
  bf16x8 r;
  r[0] = (short)f2b(a[0]); r[1] = (short)f2b(a[1]);
  r[2] = (short)f2b(a[2]); r[3] = (short)f2b(a[3]);
  r[4] = (short)f2b(b[0]); r[5] = (short)f2b(b[1]);
  r[6] = (short)f2b(b[2]); r[7] = (short)f2b(b[3]);
  return r;
}

// ======================= Phase 1: the sequential scan =======================
__global__ __launch_bounds__(256, 1)
void scan_kernel(const float* __restrict__ uin,   // [256][1024][32]
                 const float* __restrict__ x0,    // [1024][128]
                 const float* __restrict__ dtp,
                 const float* __restrict__ Wlin,  // [128][160]
                 const float* __restrict__ W1,    // [256][160]
                 const float* __restrict__ b1,    // [256]
                 const float* __restrict__ W2,    // [256][256]
                 const float* __restrict__ b2,    // [256]
                 const float* __restrict__ W3,    // [128][256]
                 const float* __restrict__ b3,    // [128]
                 u16* __restrict__ xall,          // [256][1024][128] bf16
                 float* __restrict__ out)         // xf at out[NY..]
{
  __shared__ u16 zb[16][168];   // z = [x | u] row-major (pad 168)
  __shared__ u16 h1[16][264];
  __shared__ u16 h2[16][264];

  const int tid  = threadIdx.x;
  const int wg   = blockIdx.x;            // batch rows wg*16..+15
  const int lane = tid & 63;
  const int v    = tid >> 6;              // wave 0..3
  const int ln   = lane & 15;
  const int q    = lane >> 4;

  const float dt  = dtp[0];
  const float dth = 0.5f * dt;
  const float dt6 = dt * (1.0f / 6.0f);
  const f32x4 zero4 = {0.f, 0.f, 0.f, 0.f};

  // tile ownership: S1/S2 h-tiles j=0..3 at cols 64v+16j+ln;
  // S1-lin & S3 x-tiles j=0..1 at cols 32v+16j+ln.
  // ---- resident B-fragments (B[k][n] = W[n][k]) : 312 VGPRs ----
  bf16x8 wc_h[5][4], wc_l[5][2];
#pragma unroll
  for (int kt = 0; kt < 5; kt++) {
    int k = 32 * kt + 8 * q;
#pragma unroll
    for (int j = 0; j < 4; j++)
      wc_h[kt][j] = ldw8f(W1 + (64 * v + 16 * j + ln) * NINQ + k);
#pragma unroll
    for (int j = 0; j < 2; j++)
      wc_l[kt][j] = ldw8f(Wlin + (32 * v + 16 * j + ln) * NINQ + k);
  }
  bf16x8 w2f[8][4];
#pragma unroll
  for (int kt = 0; kt < 8; kt++) {
    int k = 32 * kt + 8 * q;
#pragma unroll
    for (int j = 0; j < 4; j++)
      w2f[kt][j] = ldw8f(W2 + (64 * v + 16 * j + ln) * NFQ + k);
  }
  bf16x8 w3f[8][2];
#pragma unroll
  for (int kt = 0; kt < 8; kt++) {
    int k = 32 * kt + 8 * q;
#pragma unroll
    for (int j = 0; j < 2; j++)
      w3f[kt][j] = ldw8f(W3 + (32 * v + 16 * j + ln) * NFQ + k);
  }

  float b1v[4], b2v[4], b3v[2];
#pragma unroll
  for (int j = 0; j < 4; j++) {
    b1v[j] = b1[64 * v + 16 * j + ln];
    b2v[j] = b2[64 * v + 16 * j + ln];
  }
#pragma unroll
  for (int j = 0; j < 2; j++) b3v[j] = b3[32 * v + 16 * j + ln];

  // RK4 state (C-layout): x[rows 4q+r][col 32v+16j+ln]
  float xs[2][4], ksum[2][4];
#pragma unroll
  for (int j = 0; j < 2; j++)
#pragma unroll
    for (int r = 0; r < 4; r++)
      xs[j][r] = x0[(wg * 16 + 4 * q + r) * NXQ + 32 * v + 16 * j + ln];

  // zb init: x0 (bf16) cols 0..127, u[0] cols 128..159
  {
    int r = tid & 15, c8 = tid >> 4;      // c8 0..15 -> cols 8*c8..+7
    const float* xp = &x0[(wg * 16 + r) * NXQ + 8 * c8];
    u16 t8[8];
#pragma unroll
    for (int j = 0; j < 8; j++) t8[j] = f2b(xp[j]);
    *reinterpret_cast<bf16x8*>(&zb[r][8 * c8]) =
        *reinterpret_cast<const bf16x8*>(t8);
    const float* up = &uin[(size_t)(wg * 16 + r) * NUQ + 2 * c8];
    unsigned pk = ((unsigned)f2b(up[1]) << 16) | f2b(up[0]);
    *reinterpret_cast<unsigned*>(&zb[r][128 + 2 * c8]) = pk;
  }
  __syncthreads();

#pragma unroll 1
  for (int t = 0; t < TSTEPS; t++) {
#pragma unroll 1
    for (int e = 0; e < 4; e++) {
      f32x4 accl[2];
      // ---- S1: z @ [W1|Wlin]^T -> h1 (relu, LDS) + lin (regs) ----
      {
        bf16x8 a[5];
#pragma unroll
        for (int kt = 0; kt < 5; kt++)
          a[kt] = *reinterpret_cast<const bf16x8*>(&zb[ln][32 * kt + 8 * q]);
        f32x4 acc[4];
#pragma unroll
        for (int j = 0; j < 4; j++) acc[j] = zero4;
        accl[0] = zero4; accl[1] = zero4;
#pragma unroll
        for (int kt = 0; kt < 5; kt++) {
#pragma unroll
          for (int j = 0; j < 4; j++) acc[j] = mfma16(a[kt], wc_h[kt][j], acc[j]);
          accl[0] = mfma16(a[kt], wc_l[kt][0], accl[0]);
          accl[1] = mfma16(a[kt], wc_l[kt][1], accl[1]);
        }
#pragma unroll
        for (int j = 0; j < 4; j++) {
          int n = 64 * v + 16 * j + ln;
#pragma unroll
          for (int r = 0; r < 4; r++)
            h1[4 * q + r][n] = f2b(fmaxf(acc[j][r] + b1v[j], 0.f));
        }
      }
      __syncthreads();
      // ---- S2: h1 @ W2^T -> h2 (relu) ----
      {
        bf16x8 a[8];
#pragma unroll
        for (int kt = 0; kt < 8; kt++)
          a[kt] = *reinterpret_cast<const bf16x8*>(&h1[ln][32 * kt + 8 * q]);
        f32x4 acc[4];
#pragma unroll
        for (int j = 0; j < 4; j++) acc[j] = zero4;
#pragma unroll
        for (int kt = 0; kt < 8; kt++)
#pragma unroll
          for (int j = 0; j < 4; j++)
            acc[j] = mfma16(a[kt], w2f[kt][j], acc[j]);
#pragma unroll
        for (int j = 0; j < 4; j++) {
          int n = 64 * v + 16 * j + ln;
#pragma unroll
          for (int r = 0; r < 4; r++)
            h2[4 * q + r][n] = f2b(fmaxf(acc[j][r] + b2v[j], 0.f));
        }
      }
      __syncthreads();
      // ---- S3: h2 @ W3^T + lin + b3 -> k ; RK4 update in-register ----
      {
        bf16x8 a[8];
#pragma unroll
        for (int kt = 0; kt < 8; kt++)
          a[kt] = *reinterpret_cast<const bf16x8*>(&h2[ln][32 * kt + 8 * q]);
        f32x4 kk[2]; kk[0] = zero4; kk[1] = zero4;
#pragma unroll
        for (int kt = 0; kt < 8; kt++) {
          kk[0] = mfma16(a[kt], w3f[kt][0], kk[0]);
          kk[1] = mfma16(a[kt], w3f[kt][1], kk[1]);
        }
        const float wk = (e == 1 || e == 2) ? 2.0f : 1.0f;
        const float cn = (e == 2) ? dt : dth;
#pragma unroll
        for (int j = 0; j < 2; j++) {
          int n = 32 * v + 16 * j + ln;
          u16 zo[4];
#pragma unroll
          for (int r = 0; r < 4; r++) {
            float kv = kk[j][r] + accl[j][r] + b3v[j];
            if (e == 0) ksum[j][r] = kv; else ksum[j][r] += wk * kv;
            float xe;
            if (e == 3) { xs[j][r] += dt6 * ksum[j][r]; xe = xs[j][r]; }
            else        { xe = xs[j][r] + cn * kv; }
            zo[r] = f2b(xe);
            zb[4 * q + r][n] = zo[r];
          }
          if (e == 3) {
#pragma unroll
            for (int r = 0; r < 4; r++)
              xall[((size_t)t * BATCH + wg * 16 + 4 * q + r) * NXQ + n] = zo[r];
          }
        }
        if (e == 3 && t + 1 < TSTEPS) {
          // u[t+1] -> zb cols 128..159 (old u last read at this step's S1s)
          int r = tid & 15, c8 = tid >> 4;
          const float* up =
              &uin[((size_t)(t + 1) * BATCH + wg * 16 + r) * NUQ + 2 * c8];
          unsigned pk = ((unsigned)f2b(up[1]) << 16) | f2b(up[0]);
          *reinterpret_cast<unsigned*>(&zb[r][128 + 2 * c8]) = pk;
        }
      }
      __syncthreads();
    }
  }

  // x_final (f32)
#pragma unroll
  for (int j = 0; j < 2; j++)
#pragma unroll
    for (int r = 0; r < 4; r++)
      out[NY + (size_t)(wg * 16 + 4 * q + r) * NXQ + 32 * v + 16 * j + ln] =
          xs[j][r];
}

// ======================= Phase 2: bulk out_net GEMM =========================
__global__ __launch_bounds__(512, 2)
void outnet_kernel(const u16* __restrict__ xall,  // [rows][128] bf16
                   const float* __restrict__ Wo1, const float* __restrict__ bo1,
                   const float* __restrict__ Wo2, const float* __restrict__ bo2,
                   const float* __restrict__ Wo3, const float* __restrict__ bo3,
                   float* __restrict__ out,       // y [rows][128] f32
                   int slab0, int slab_end, int spw)
{
  __shared__ u16 h1[2][16][264];
  __shared__ u16 h2[2][16][264];

  const int tid  = threadIdx.x;
  const int lane = tid & 63;
  const int v    = tid >> 6;
  const int ln   = lane & 15;
  const int q    = lane >> 4;
  const int n1   = 16 * v + ln;
  const int n2   = 128 + n1;
  const f32x4 zero4 = {0.f, 0.f, 0.f, 0.f};

  bf16x8 f1[4][2];
#pragma unroll
  for (int kt = 0; kt < 4; kt++) {
    int k = 32 * kt + 8 * q;
    f1[kt][0] = ldw8f(Wo1 + n1 * NXQ + k);
    f1[kt][1] = ldw8f(Wo1 + n2 * NXQ + k);
  }
  bf16x8 f2[8][2];
#pragma unroll
  for (int kt = 0; kt < 8; kt++) {
    int k = 32 * kt + 8 * q;
    f2[kt][0] = ldw8f(Wo2 + n1 * NFQ + k);
    f2[kt][1] = ldw8f(Wo2 + n2 * NFQ + k);
  }
  bf16x8 f3[8];
#pragma unroll
  for (int kt = 0; kt < 8; kt++)
    f3[kt] = ldw8f(Wo3 + n1 * NFQ + 32 * kt + 8 * q);

  const float c1a = bo1[n1], c1b = bo1[n2];
  const float c2a = bo2[n1], c2b = bo2[n2];
  const float c3  = bo3[n1];

  const int s0  = slab0 + (int)blockIdx.x * spw;
  int cnt = slab_end - s0; if (cnt > spw) cnt = spw;
  if (cnt <= 0) return;

  bf16x8 a[4], an[4];
#pragma unroll
  for (int kt = 0; kt < 4; kt++)
    a[kt] = *reinterpret_cast<const bf16x8*>(
        &xall[((size_t)16 * s0 + ln) * NXQ + 32 * kt + 8 * q]);

#pragma unroll 1
  for (int i = 0; i < cnt; i++) {
    const int s = s0 + i, par = i & 1;
    if (i + 1 < cnt) {
#pragma unroll
      for (int kt = 0; kt < 4; kt++)
        an[kt] = *reinterpret_cast<const bf16x8*>(
            &xall[((size_t)16 * (s + 1) + ln) * NXQ + 32 * kt + 8 * q]);
    }
    {
      f32x4 d0 = zero4, d1 = zero4;
#pragma unroll
      for (int kt = 0; kt < 4; kt++) {
        d0 = mfma16(a[kt], f1[kt][0], d0);
        d1 = mfma16(a[kt], f1[kt][1], d1);
      }
#pragma unroll
      for (int r = 0; r < 4; r++) {
        h1[par][4 * q + r][n1] = f2b(fmaxf(d0[r] + c1a, 0.f));
        h1[par][4 * q + r][n2] = f2b(fmaxf(d1[r] + c1b, 0.f));
      }
    }
    __syncthreads();
    {
      bf16x8 c[8];
#pragma unroll
      for (int kt = 0; kt < 8; kt++)
        c[kt] = *reinterpret_cast<const bf16x8*>(&h1[par][ln][32 * kt + 8 * q]);
      f32x4 e0 = zero4, e1 = zero4;
#pragma unroll
      for (int kt = 0; kt < 8; kt++) {
        e0 = mfma16(c[kt], f2[kt][0], e0);
        e1 = mfma16(c[kt], f2[kt][1], e1);
      }
#pragma unroll
      for (int r = 0; r < 4; r++) {
        h2[par][4 * q + r][n1] = f2b(fmaxf(e0[r] + c2a, 0.f));
        h2[par][4 * q + r][n2] = f2b(fmaxf(e1[r] + c2b, 0.f));
      }
    }
    __syncthreads();
    {
      bf16x8 g[8];
#pragma unroll
      for (int kt = 0; kt < 8; kt++)
        g[kt] = *reinterpret_cast<const bf16x8*>(&h2[par][ln][32 * kt + 8 * q]);
      f32x4 y = zero4;
#pragma unroll
      for (int kt = 0; kt < 8; kt++) y = mfma16(g[kt], f3[kt], y);
#pragma unroll
      for (int r = 0; r < 4; r++)
        out[((size_t)16 * s + 4 * q + r) * NXQ + n1] = y[r] + c3;
    }
#pragma unroll
    for (int kt = 0; kt < 4; kt++) a[kt] = an[kt];
  }
}

extern "C" void kernel_launch(void* const* d_in, const int* in_sizes, int n_in,
                              void* d_out, int out_size, void* d_ws, size_t ws_size,
                              hipStream_t stream) {
  const float* uin  = (const float*)d_in[0];
  const float* x0   = (const float*)d_in[1];
  const float* dtp  = (const float*)d_in[2];
  const float* Wlin = (const float*)d_in[3];
  const float* W1   = (const float*)d_in[4];
  const float* b1   = (const float*)d_in[5];
  const float* W2   = (const float*)d_in[6];
  const float* b2   = (const float*)d_in[7];
  const float* W3   = (const float*)d_in[8];
  const float* b3   = (const float*)d_in[9];
  const float* Wo1  = (const float*)d_in[10];
  const float* bo1  = (const float*)d_in[11];
  const float* Wo2  = (const float*)d_in[12];
  const float* bo2  = (const float*)d_in[13];
  const float* Wo3  = (const float*)d_in[14];
  const float* bo3  = (const float*)d_in[15];
  float* out = (float*)d_out;

  const size_t xall_bytes = NY * sizeof(u16);   // 64 MiB
  const bool ws_ok = (ws_size >= xall_bytes);
  u16* xall = ws_ok ? (u16*)d_ws : (u16*)d_out;

  scan_kernel<<<dim3(64), dim3(256), 0, stream>>>(
      uin, x0, dtp, Wlin, W1, b1, W2, b2, W3, b3, xall, out);

  const int nslab = TSTEPS * BATCH / 16;        // 16384
  if (ws_ok) {
    const int spw = 32;
    outnet_kernel<<<dim3(nslab / spw), dim3(512), 0, stream>>>(
        xall, Wo1, bo1, Wo2, bo2, Wo3, bo3, out, 0, nslab, spw);
  } else {
    for (int S = nslab / 2; S >= 1; S >>= 1) {
      int grid = S < 512 ? S : 512;
      int spw  = (S + grid - 1) / grid;
      outnet_kernel<<<dim3(grid), dim3(512), 0, stream>>>(
          xall, Wo1, bo1, Wo2, bo2, Wo3, bo3, out, S, 2 * S, spw);
    }
    outnet_kernel<<<dim3(1), dim3(512), 0, stream>>>(
        xall, Wo1, bo1, Wo2, bo2, Wo3, bo3, out, 0, 1, 1);
  }
}

// Round 6
// 1911.622 us; speedup vs baseline: 1.3739x; 1.3739x over previous
//
#include <hip/hip_runtime.h>

// ODELayer RK4 scan. R6 = R4 structure (64 WG x 512 thr, 8 waves, 2/SIMD,
// proven 1505us scan) + fp8(e4m3) MLP branch:
//   - h1/h2 activations in LDS as fp8 (b64 A-frag reads, half of b128)
//   - W2/W3 resident B-fragments as fp8 (fewer weight VGPRs than R4)
//   - lin path (z, Wlin, accl) stays bf16 -- it dominates dx numerically.
//   Static exact scales: h1*2^10, W*2^12, h2*2^20, final *2^-32.
// Phase 2 (outnet) unchanged bf16.

#define TSTEPS 256
#define BATCH  1024
#define NUQ    32
#define NXQ    128
#define NFQ    256
#define NINQ   160
#define NY     ((size_t)TSTEPS * BATCH * NXQ)

typedef __attribute__((ext_vector_type(8))) short bf16x8;
typedef __attribute__((ext_vector_type(4))) float f32x4;
typedef unsigned short u16;

__device__ __forceinline__ u16 f2b(float f) {
  unsigned u = __float_as_uint(f);
  u = (u + 0x7FFFu + ((u >> 16) & 1u)) >> 16;
  return (u16)u;
}
__device__ __forceinline__ f32x4 mfma16(bf16x8 a, bf16x8 b, f32x4 c) {
  return __builtin_amdgcn_mfma_f32_16x16x32_bf16(a, b, c, 0, 0, 0);
}
__device__ __forceinline__ f32x4 mfma8(long a, long b, f32x4 c) {
  return __builtin_amdgcn_mfma_f32_16x16x32_fp8_fp8(a, b, c, 0, 0, 0);
}
__device__ __forceinline__ bf16x8 ldw8f(const float* p) {
  f32x4 a = *reinterpret_cast<const f32x4*>(p);
  f32x4 b = *reinterpret_cast<const f32x4*>(p + 4);
  bf16x8 r;
  r[0] = (short)f2b(a[0]); r[1] = (short)f2b(a[1]);
  r[2] = (short)f2b(a[2]); r[3] = (short)f2b(a[3]);
  r[4] = (short)f2b(b[0]); r[5] = (short)f2b(b[1]);
  r[6] = (short)f2b(b[2]); r[7] = (short)f2b(b[3]);
  return r;
}
// 8 consecutive f32 weights * scale -> packed fp8 e4m3 (byte j <-> elem j)
__device__ __forceinline__ long ldw8f8(const float* p, float s) {
  f32x4 a = *reinterpret_cast<const f32x4*>(p);
  f32x4 b = *reinterpret_cast<const f32x4*>(p + 4);
  int lo = 0, hi = 0;
  lo = __builtin_amdgcn_cvt_pk_fp8_f32(a[0] * s, a[1] * s, lo, false);
  lo = __builtin_amdgcn_cvt_pk_fp8_f32(a[2] * s, a[3] * s, lo, true);
  hi = __builtin_amdgcn_cvt_pk_fp8_f32(b[0] * s, b[1] * s, hi, false);
  hi = __builtin_amdgcn_cvt_pk_fp8_f32(b[2] * s, b[3] * s, hi, true);
  return ((long)(unsigned)hi << 32) | (unsigned)lo;
}
__device__ __forceinline__ unsigned char f2e4(float v) {
  int t = __builtin_amdgcn_cvt_pk_fp8_f32(v, 0.f, 0, false);
  return (unsigned char)(t & 0xFF);
}

// ======================= Phase 1: the sequential scan =======================
__global__ __launch_bounds__(512, 2)
void scan_kernel(const float* __restrict__ uin,   // [256][1024][32]
                 const float* __restrict__ x0,    // [1024][128]
                 const float* __restrict__ dtp,
                 const float* __restrict__ Wlin,  // [128][160]
                 const float* __restrict__ W1,    // [256][160]
                 const float* __restrict__ b1,    // [256]
                 const float* __restrict__ W2,    // [256][256]
                 const float* __restrict__ b2,    // [256]
                 const float* __restrict__ W3,    // [128][256]
                 const float* __restrict__ b3,    // [128]
                 u16* __restrict__ xall,          // [256][1024][128] bf16
                 float* __restrict__ out)         // xf at out[NY..]
{
  __shared__ __align__(16) u16 zb[16][168];            // z=[x|u] bf16 row-major
  __shared__ __align__(16) unsigned char h1f[16][272]; // h1 fp8 (pad 272)
  __shared__ __align__(16) unsigned char h2f[16][272]; // h2 fp8

  const int tid  = threadIdx.x;
  const int wg   = blockIdx.x;            // batch rows wg*16..+15
  const int lane = tid & 63;
  const int v    = tid >> 6;              // wave 0..7
  const int ln   = lane & 15;
  const int q    = lane >> 4;

  const float dt  = dtp[0];
  const float dth = 0.5f * dt;
  const float dt6 = dt * (1.0f / 6.0f);
  const f32x4 zero4 = {0.f, 0.f, 0.f, 0.f};

  // scales (exact powers of 2)
  const float SH1 = 1024.0f;              // h1 stored * 2^10
  const float SW  = 4096.0f;              // W2,W3 stored * 2^12
  const float SB2 = 4194304.0f;           // 2^22 (acc2 scale)
  const float SH2 = 0.25f;                // 2^20 / 2^22
  const float SK  = 1.0f / 4294967296.0f; // 2^-32

  // wave v owns cols n1=16v+ln and (N=256 tiles) n2=128+n1
  const int n1 = 16 * v + ln;
  const int n2 = 128 + n1;

  // ---- resident B-fragments ----
  bf16x8 wc[5][3];                        // S1: W1 tiles n1,n2 (bf16), Wlin n1
#pragma unroll
  for (int kt = 0; kt < 5; kt++) {
    int k = 32 * kt + 8 * q;
    wc[kt][0] = ldw8f(W1 + n1 * NINQ + k);
    wc[kt][1] = ldw8f(W1 + n2 * NINQ + k);
    wc[kt][2] = ldw8f(Wlin + n1 * NINQ + k);
  }
  long w2f[8][2];                         // S2: fp8, tiles n1,n2
#pragma unroll
  for (int kt = 0; kt < 8; kt++) {
    int k = 32 * kt + 8 * q;
    w2f[kt][0] = ldw8f8(W2 + n1 * NFQ + k, SW);
    w2f[kt][1] = ldw8f8(W2 + n2 * NFQ + k, SW);
  }
  long w3f[8];                            // S3: fp8, tile n1
#pragma unroll
  for (int kt = 0; kt < 8; kt++)
    w3f[kt] = ldw8f8(W3 + n1 * NFQ + 32 * kt + 8 * q, SW);

  const float b1a = b1[n1], b1b = b1[n2];
  const float b2a = b2[n1] * SB2, b2b = b2[n2] * SB2;
  const float b3a = b3[n1];

  // RK4 state in C-layout: lane holds x[rows 4q+r][col n1]
  float xs[4], ksum[4];
#pragma unroll
  for (int r = 0; r < 4; r++)
    xs[r] = x0[(wg * 16 + 4 * q + r) * NXQ + n1];

  // zb init: bf16(x0) cols 0..127 + u[0] cols 128..159
  {
    int r = tid & 15, cG = tid >> 4;      // cG 0..31 -> cols 4cG..+3
    const float* xp = &x0[(wg * 16 + r) * NXQ + 4 * cG];
    u16 t4[4];
#pragma unroll
    for (int j = 0; j < 4; j++) t4[j] = f2b(xp[j]);
    *reinterpret_cast<unsigned long long*>(&zb[r][4 * cG]) =
        *reinterpret_cast<const unsigned long long*>(t4);
    zb[ln][128 + 4 * v + q] =
        f2b(uin[(size_t)(wg * 16 + ln) * NUQ + 4 * v + q]);
  }
  __syncthreads();

#pragma unroll 1
  for (int t = 0; t < TSTEPS; t++) {
#pragma unroll 1
    for (int e = 0; e < 4; e++) {
      f32x4 accl;
      // ---- S1: z @ [W1|Wlin]^T -> h1 (fp8, *2^10) + lin (regs, bf16 math) ----
      {
        bf16x8 a[5];
#pragma unroll
        for (int kt = 0; kt < 5; kt++)
          a[kt] = *reinterpret_cast<const bf16x8*>(&zb[ln][32 * kt + 8 * q]);
        f32x4 acc0 = zero4, acc1 = zero4; accl = zero4;
#pragma unroll
        for (int kt = 0; kt < 5; kt++) {
          acc0 = mfma16(a[kt], wc[kt][0], acc0);
          acc1 = mfma16(a[kt], wc[kt][1], acc1);
          accl = mfma16(a[kt], wc[kt][2], accl);
        }
#pragma unroll
        for (int r = 0; r < 4; r++) {
          h1f[4 * q + r][n1] = f2e4(fmaxf(acc0[r] + b1a, 0.f) * SH1);
          h1f[4 * q + r][n2] = f2e4(fmaxf(acc1[r] + b1b, 0.f) * SH1);
        }
      }
      __syncthreads();
      // ---- S2: h1(fp8) @ W2(fp8)^T -> h2 (fp8, *2^20) ----
      {
        long a[8];
#pragma unroll
        for (int kt = 0; kt < 8; kt++)
          a[kt] = *reinterpret_cast<const long*>(&h1f[ln][32 * kt + 8 * q]);
        f32x4 d0 = zero4, d1 = zero4;
#pragma unroll
        for (int kt = 0; kt < 8; kt++) {
          d0 = mfma8(a[kt], w2f[kt][0], d0);
          d1 = mfma8(a[kt], w2f[kt][1], d1);
        }
#pragma unroll
        for (int r = 0; r < 4; r++) {
          h2f[4 * q + r][n1] = f2e4(fmaxf(d0[r] + b2a, 0.f) * SH2);
          h2f[4 * q + r][n2] = f2e4(fmaxf(d1[r] + b2b, 0.f) * SH2);
        }
      }
      __syncthreads();
      // ---- S3: h2(fp8) @ W3(fp8)^T * 2^-32 + lin + b3 -> k ; RK4 update ----
      {
        long a[8];
#pragma unroll
        for (int kt = 0; kt < 8; kt++)
          a[kt] = *reinterpret_cast<const long*>(&h2f[ln][32 * kt + 8 * q]);
        f32x4 kk = zero4;
#pragma unroll
        for (int kt = 0; kt < 8; kt++) kk = mfma8(a[kt], w3f[kt], kk);

        const float wk = (e == 1 || e == 2) ? 2.0f : 1.0f;
        const float cn = (e == 2) ? dt : dth;
        u16 zo[4];
#pragma unroll
        for (int r = 0; r < 4; r++) {
          float kv = kk[r] * SK + accl[r] + b3a;
          if (e == 0) ksum[r] = kv; else ksum[r] += wk * kv;
          float xe;
          if (e == 3) { xs[r] += dt6 * ksum[r]; xe = xs[r]; }
          else        { xe = xs[r] + cn * kv; }
          zo[r] = f2b(xe);
          zb[4 * q + r][n1] = zo[r];
        }
        if (e == 3) {
#pragma unroll
          for (int r = 0; r < 4; r++)
            xall[((size_t)t * BATCH + wg * 16 + 4 * q + r) * NXQ + n1] = zo[r];
          if (t + 1 < TSTEPS)
            zb[ln][128 + 4 * v + q] = f2b(
                uin[((size_t)(t + 1) * BATCH + wg * 16 + ln) * NUQ + 4 * v + q]);
        }
      }
      __syncthreads();
    }
  }

  // x_final (f32)
#pragma unroll
  for (int r = 0; r < 4; r++)
    out[NY + (size_t)(wg * 16 + 4 * q + r) * NXQ + n1] = xs[r];
}

// ======================= Phase 2: bulk out_net GEMM (bf16) ==================
__global__ __launch_bounds__(512, 2)
void outnet_kernel(const u16* __restrict__ xall,  // [rows][128] bf16
                   const float* __restrict__ Wo1, const float* __restrict__ bo1,
                   const float* __restrict__ Wo2, const float* __restrict__ bo2,
                   const float* __restrict__ Wo3, const float* __restrict__ bo3,
                   float* __restrict__ out,       // y [rows][128] f32
                   int slab0, int slab_end, int spw)
{
  __shared__ u16 h1[2][16][264];
  __shared__ u16 h2[2][16][264];

  const int tid  = threadIdx.x;
  const int lane = tid & 63;
  const int v    = tid >> 6;
  const int ln   = lane & 15;
  const int q    = lane >> 4;
  const int n1   = 16 * v + ln;
  const int n2   = 128 + n1;
  const f32x4 zero4 = {0.f, 0.f, 0.f, 0.f};

  bf16x8 f1[4][2];
#pragma unroll
  for (int kt = 0; kt < 4; kt++) {
    int k = 32 * kt + 8 * q;
    f1[kt][0] = ldw8f(Wo1 + n1 * NXQ + k);
    f1[kt][1] = ldw8f(Wo1 + n2 * NXQ + k);
  }
  bf16x8 f2[8][2];
#pragma unroll
  for (int kt = 0; kt < 8; kt++) {
    int k = 32 * kt + 8 * q;
    f2[kt][0] = ldw8f(Wo2 + n1 * NFQ + k);
    f2[kt][1] = ldw8f(Wo2 + n2 * NFQ + k);
  }
  bf16x8 f3[8];
#pragma unroll
  for (int kt = 0; kt < 8; kt++)
    f3[kt] = ldw8f(Wo3 + n1 * NFQ + 32 * kt + 8 * q);

  const float c1a = bo1[n1], c1b = bo1[n2];
  const float c2a = bo2[n1], c2b = bo2[n2];
  const float c3  = bo3[n1];

  const int s0  = slab0 + (int)blockIdx.x * spw;
  int cnt = slab_end - s0; if (cnt > spw) cnt = spw;
  if (cnt <= 0) return;

  bf16x8 a[4], an[4];
#pragma unroll
  for (int kt = 0; kt < 4; kt++)
    a[kt] = *reinterpret_cast<const bf16x8*>(
        &xall[((size_t)16 * s0 + ln) * NXQ + 32 * kt + 8 * q]);

#pragma unroll 1
  for (int i = 0; i < cnt; i++) {
    const int s = s0 + i, par = i & 1;
    if (i + 1 < cnt) {
#pragma unroll
      for (int kt = 0; kt < 4; kt++)
        an[kt] = *reinterpret_cast<const bf16x8*>(
            &xall[((size_t)16 * (s + 1) + ln) * NXQ + 32 * kt + 8 * q]);
    }
    {
      f32x4 d0 = zero4, d1 = zero4;
#pragma unroll
      for (int kt = 0; kt < 4; kt++) {
        d0 = mfma16(a[kt], f1[kt][0], d0);
        d1 = mfma16(a[kt], f1[kt][1], d1);
      }
#pragma unroll
      for (int r = 0; r < 4; r++) {
        h1[par][4 * q + r][n1] = f2b(fmaxf(d0[r] + c1a, 0.f));
        h1[par][4 * q + r][n2] = f2b(fmaxf(d1[r] + c1b, 0.f));
      }
    }
    __syncthreads();
    {
      bf16x8 c[8];
#pragma unroll
      for (int kt = 0; kt < 8; kt++)
        c[kt] = *reinterpret_cast<const bf16x8*>(&h1[par][ln][32 * kt + 8 * q]);
      f32x4 e0 = zero4, e1 = zero4;
#pragma unroll
      for (int kt = 0; kt < 8; kt++) {
        e0 = mfma16(c[kt], f2[kt][0], e0);
        e1 = mfma16(c[kt], f2[kt][1], e1);
      }
#pragma unroll
      for (int r = 0; r < 4; r++) {
        h2[par][4 * q + r][n1] = f2b(fmaxf(e0[r] + c2a, 0.f));
        h2[par][4 * q + r][n2] = f2b(fmaxf(e1[r] + c2b, 0.f));
      }
    }
    __syncthreads();
    {
      bf16x8 g[8];
#pragma unroll
      for (int kt = 0; kt < 8; kt++)
        g[kt] = *reinterpret_cast<const bf16x8*>(&h2[par][ln][32 * kt + 8 * q]);
      f32x4 y = zero4;
#pragma unroll
      for (int kt = 0; kt < 8; kt++) y = mfma16(g[kt], f3[kt], y);
#pragma unroll
      for (int r = 0; r < 4; r++)
        out[((size_t)16 * s + 4 * q + r) * NXQ + n1] = y[r] + c3;
    }
#pragma unroll
    for (int kt = 0; kt < 4; kt++) a[kt] = an[kt];
  }
}

extern "C" void kernel_launch(void* const* d_in, const int* in_sizes, int n_in,
                              void* d_out, int out_size, void* d_ws, size_t ws_size,
                              hipStream_t stream) {
  const float* uin  = (const float*)d_in[0];
  const float* x0   = (const float*)d_in[1];
  const float* dtp  = (const float*)d_in[2];
  const float* Wlin = (const float*)d_in[3];
  const float* W1   = (const float*)d_in[4];
  const float* b1   = (const float*)d_in[5];
  const float* W2   = (const float*)d_in[6];
  const float* b2   = (const float*)d_in[7];
  const float* W3   = (const float*)d_in[8];
  const float* b3   = (const float*)d_in[9];
  const float* Wo1  = (const float*)d_in[10];
  const float* bo1  = (const float*)d_in[11];
  const float* Wo2  = (const float*)d_in[12];
  const float* bo2  = (const float*)d_in[13];
  const float* Wo3  = (const float*)d_in[14];
  const float* bo3  = (const float*)d_in[15];
  float* out = (float*)d_out;

  const size_t xall_bytes = NY * sizeof(u16);   // 64 MiB
  const bool ws_ok = (ws_size >= xall_bytes);
  u16* xall = ws_ok ? (u16*)d_ws : (u16*)d_out;

  scan_kernel<<<dim3(64), dim3(512), 0, stream>>>(
      uin, x0, dtp, Wlin, W1, b1, W2, b2, W3, b3, xall, out);

  const int nslab = TSTEPS * BATCH / 16;        // 16384
  if (ws_ok) {
    const int spw = 32;
    outnet_kernel<<<dim3(nslab / spw), dim3(512), 0, stream>>>(
        xall, Wo1, bo1, Wo2, bo2, Wo3, bo3, out, 0, nslab, spw);
  } else {
    for (int S = nslab / 2; S >= 1; S >>= 1) {
      int grid = S < 512 ? S : 512;
      int spw  = (S + grid - 1) / grid;
      outnet_kernel<<<dim3(grid), dim3(512), 0, stream>>>(
          xall, Wo1, bo1, Wo2, bo2, Wo3, bo3, out, S, 2 * S, spw);
    }
    outnet_kernel<<<dim3(1), dim3(512), 0, stream>>>(
        xall, Wo1, bo1, Wo2, bo2, Wo3, bo3, out, 0, 1, 1);
  }
}